// Round 3
// baseline (409.790 us; speedup 1.0000x reference)
//
#include <hip/hip_runtime.h>
#include <hip/hip_bf16.h>

// LightAttention: Z = softmax_n(Q/d4) @ [ softmax_n(K/d4)^T @ V ]
// Folded: E=exp(Q/d4), F=exp(K/d4), Sq/Sk col-sums over n,
//   Bm[d,e] = sum_n F[n,d] V[n,e];  Ct[e,d] = Bm[d,e]/(Sq[d]Sk[d]);  Z = E @ Ct^T.
//
// Round-7: proj_q/proj_kv rebuilt as counted-vmcnt gload_lds pipeline.
//  - X fp32 staged direct global->LDS (async), BK=64, 2 bufs x 32 KB,
//    XOR piece-swizzle (piece ^= row&15) via pre-swizzled global source.
//  - vmcnt(8) + lgkmcnt(0) + barrier per step: next-chunk staging loads stay
//    in flight across the barrier (true T4); no register staging pipeline.
//  - fp32->bf16 conversion at fragment-read time (2x ds_read_b128 + cvt),
//    hidden under the 32-MFMA phase.
//  - W operand direct-to-reg, named A/B buffers, fully macro-unrolled steps
//    (zero runtime-indexed register arrays).
//  - bm_gemm / z_gemm / wt / sk / scale unchanged from round 6.

typedef __bf16 bf16_t;
typedef __attribute__((ext_vector_type(8))) __bf16 bf16x8;
typedef __attribute__((ext_vector_type(4))) __bf16 bf16x4;
typedef __attribute__((ext_vector_type(4))) float f32x4;

#define MFMA_BF16 __builtin_amdgcn_mfma_f32_16x16x32_bf16

__device__ inline void async_ld16(const void* g, void* l) {
  __builtin_amdgcn_global_load_lds(
      (const __attribute__((address_space(1))) void*)g,
      (__attribute__((address_space(3))) void*)l, 16, 0, 0);
}

#define INV_D4 0.2102241038134287f  // 1 / 512^0.25

// Barrier for gload_lds staging in bm/z (round-6 style): drain vm + lgkm.
#define BAR_VM_LGKM()                                             \
  do {                                                            \
    asm volatile("s_waitcnt vmcnt(0) lgkmcnt(0)" ::: "memory");   \
    __builtin_amdgcn_s_barrier();                                 \
  } while (0)

// Counted step boundary for proj kernels: drain all but the 8 newest VMEM ops
// (the W-register loads for the next step); staged LDS chunk is guaranteed.
#define BAR_VM8_LGKM()                                            \
  do {                                                            \
    asm volatile("s_waitcnt vmcnt(8) lgkmcnt(0)" ::: "memory");   \
    __builtin_amdgcn_s_barrier();                                 \
  } while (0)

// ---- proj staging: one BK=64 f32 chunk (128 rows x 64 k = 32 KB) ----------
// Wave w stages rows w*32 .. w*32+31; 8 instrs, each 4 rows x 256 B (full
// lines).  Global source piece is pre-XOR-swizzled so linear LDS + swizzled
// read form an involution (rule 21).
#define STAGE_X(LBUF, KS)                                                  \
  _Pragma("unroll") for (int i_ = 0; i_ < 8; ++i_) {                       \
    const int rw_ = w * 32 + i_ * 4 + (lane >> 4);                         \
    const int pc_ = (lane & 15) ^ (rw_ & 15);                              \
    async_ld16(Xb + (size_t)rw_ * 512 + (KS) * 64 + pc_ * 4,               \
               (char*)(LBUF) + (w * 32 + i_ * 4) * 256);                   \
  }

// Read one bf16x8 fragment (8 k-consecutive f32) from the swizzled f32 chunk.
// row in [0,128), p0 = 16B-piece index (k = p0*4 .. p0*4+7).
__device__ inline bf16x8 frag_cvt(const float* lbuf, int row, int p0) {
  const char* base = (const char*)lbuf + row * 256;
  const int s = row & 15;
  f32x4 a = *(const f32x4*)(base + (((p0 + 0) ^ s) << 4));
  f32x4 b = *(const f32x4*)(base + (((p0 + 1) ^ s) << 4));
  bf16x8 r;
  r[0] = (__bf16)a[0]; r[1] = (__bf16)a[1]; r[2] = (__bf16)a[2]; r[3] = (__bf16)a[3];
  r[4] = (__bf16)b[0]; r[5] = (__bf16)b[1]; r[6] = (__bf16)b[2]; r[7] = (__bf16)b[3];
  return r;
}

// ---------------- W transpose+convert: W[in][out] f32 -> Wt[out][in] bf16 ----
__global__ __launch_bounds__(256) void wt_kernel(
    const float* __restrict__ Wq, const float* __restrict__ Wk,
    const float* __restrict__ Wv, bf16_t* __restrict__ Wt) {
  const int z = blockIdx.z;
  const float* W = (z == 0) ? Wq : (z == 1) ? Wk : Wv;
  bf16_t* O = Wt + (size_t)z * 262144;
  __shared__ __align__(16) bf16_t tile[64 * 72];
  const int t = threadIdx.x;
  const int r = t >> 2;
  const int c4 = (t & 3) * 16;
  const int in0 = blockIdx.x * 64, out0 = blockIdx.y * 64;
  const float* src = W + (size_t)(in0 + r) * 512 + out0 + c4;
#pragma unroll
  for (int i = 0; i < 4; ++i) {
    float4 f = ((const float4*)src)[i];
    tile[(c4 + i * 4 + 0) * 72 + r] = (__bf16)f.x;
    tile[(c4 + i * 4 + 1) * 72 + r] = (__bf16)f.y;
    tile[(c4 + i * 4 + 2) * 72 + r] = (__bf16)f.z;
    tile[(c4 + i * 4 + 3) * 72 + r] = (__bf16)f.w;
  }
  __syncthreads();
  bf16x8* dst = (bf16x8*)(O + (size_t)(out0 + r) * 512 + in0 + c4);
  const bf16x8* s = (const bf16x8*)(tile + r * 72 + c4);
  dst[0] = s[0];
  dst[1] = s[1];
}

// ---------------- proj_q: Eq[n][d]=exp((Xq@Wq+b)/d4), 128m x 128n tiles -----
__global__ __launch_bounds__(256, 2) void proj_q(
    const float* __restrict__ Xq, const bf16_t* __restrict__ Wt,
    const float* __restrict__ bias, bf16_t* __restrict__ Eq,
    float* __restrict__ Sq) {
  __shared__ __align__(16) float Xf[2][8192];  // 2 x 32 KB swizzled f32 chunks

  const int t = threadIdx.x;
  const int lane = t & 63, w = t >> 6;
  const int quad = lane >> 4, l15 = lane & 15;
  const int m0 = blockIdx.x * 128;
  const int n0 = blockIdx.y * 128;
  const int m_off = (w & 1) * 64, n_off = (w >> 1) * 64;

  f32x4 acc[4][4];
  const f32x4 zero4 = {0.f, 0.f, 0.f, 0.f};
#pragma unroll
  for (int i = 0; i < 4; ++i)
#pragma unroll
    for (int j = 0; j < 4; ++j) acc[i][j] = zero4;

  const float* Xb = Xq + (size_t)m0 * 512;
  const bf16_t* wbase = Wt + (size_t)(n0 + n_off + l15) * 512 + quad * 8;

  bf16x8 wA[4][2], wB[4][2];

#define Q_LOAD_W(WBUF, KS)                                                 \
  _Pragma("unroll") for (int ni_ = 0; ni_ < 4; ++ni_)                      \
    _Pragma("unroll") for (int u_ = 0; u_ < 2; ++u_)                       \
      WBUF[ni_][u_] =                                                      \
          *(const bf16x8*)(wbase + ni_ * 8192 + (KS) * 64 + u_ * 32);

#define Q_STEP(KS, CUR, NXT, WC, WN, FULL)                                 \
  {                                                                        \
    if (FULL) {                                                            \
      STAGE_X(NXT, (KS) + 1);                                              \
      asm volatile("" ::: "memory");                                       \
      Q_LOAD_W(WN, (KS) + 1);                                              \
    }                                                                      \
    _Pragma("unroll") for (int u = 0; u < 2; ++u)                          \
      _Pragma("unroll") for (int mi = 0; mi < 4; ++mi) {                   \
        bf16x8 ax = frag_cvt(CUR, m_off + mi * 16 + l15, u * 8 + quad * 2);\
        _Pragma("unroll") for (int ni = 0; ni < 4; ++ni)                   \
          acc[mi][ni] = MFMA_BF16(ax, WC[ni][u], acc[mi][ni], 0, 0, 0);    \
      }                                                                    \
    if (FULL) BAR_VM8_LGKM();                                              \
  }

  STAGE_X(Xf[0], 0);
  asm volatile("" ::: "memory");
  Q_LOAD_W(wA, 0);
  BAR_VM8_LGKM();

  Q_STEP(0, Xf[0], Xf[1], wA, wB, true);
  Q_STEP(1, Xf[1], Xf[0], wB, wA, true);
  Q_STEP(2, Xf[0], Xf[1], wA, wB, true);
  Q_STEP(3, Xf[1], Xf[0], wB, wA, true);
  Q_STEP(4, Xf[0], Xf[1], wA, wB, true);
  Q_STEP(5, Xf[1], Xf[0], wB, wA, true);
  Q_STEP(6, Xf[0], Xf[1], wA, wB, true);
  Q_STEP(7, Xf[1], Xf[0], wB, wA, false);

  const int b = m0 >> 12;
  float cs[4] = {0.f, 0.f, 0.f, 0.f};
#pragma unroll
  for (int ni = 0; ni < 4; ++ni) {
    const int col = n0 + n_off + ni * 16 + l15;
    const float bv_ = bias[col];
#pragma unroll
    for (int mi = 0; mi < 4; ++mi)
#pragma unroll
      for (int r = 0; r < 4; ++r) {
        const int row = m0 + m_off + mi * 16 + quad * 4 + r;
        float v = __expf((acc[mi][ni][r] + bv_) * INV_D4);
        Eq[(size_t)row * 512 + col] = (bf16_t)v;
        cs[ni] += v;
      }
  }
#pragma unroll
  for (int ni = 0; ni < 4; ++ni) {
    cs[ni] += __shfl_xor(cs[ni], 16);
    cs[ni] += __shfl_xor(cs[ni], 32);
  }
  if (lane < 16) {
#pragma unroll
    for (int ni = 0; ni < 4; ++ni)
      atomicAdd(&Sq[b * 512 + n0 + n_off + ni * 16 + lane], cs[ni]);
  }
#undef Q_STEP
#undef Q_LOAD_W
}

// ---------------- proj_kv: Ft/Vt[b][d][n], 128d x 128n tiles ----------------
__global__ __launch_bounds__(256, 2) void proj_kv(
    const float* __restrict__ xk, const float* __restrict__ xv,
    const bf16_t* __restrict__ Wt, const float* __restrict__ bk,
    const float* __restrict__ bv, bf16_t* __restrict__ Ft,
    bf16_t* __restrict__ Vt) {
  const int z = blockIdx.z + 1;  // 1=K, 2=V
  const float* X = (z == 1) ? xk : xv;
  const float* bias = (z == 1) ? bk : bv;
  const bf16_t* W = Wt + (size_t)z * 262144;
  bf16_t* Out = (z == 1) ? Ft : Vt;
  const bool expm = (z == 1);

  __shared__ __align__(16) float Xf[2][8192];

  const int t = threadIdx.x;
  const int lane = t & 63, w = t >> 6;
  const int quad = lane >> 4, l15 = lane & 15;
  const int ng = blockIdx.x * 128;   // global n over 32768
  const int d0 = blockIdx.y * 128;   // d tile
  const int d_off = (w & 1) * 64, n_off = (w >> 1) * 64;

  f32x4 acc[4][4];
  const f32x4 zero4 = {0.f, 0.f, 0.f, 0.f};
#pragma unroll
  for (int i = 0; i < 4; ++i)
#pragma unroll
    for (int j = 0; j < 4; ++j) acc[i][j] = zero4;

  const float* Xb = X + (size_t)ng * 512;
  const bf16_t* wbase = W + (size_t)(d0 + d_off + l15) * 512 + quad * 8;

  bf16x8 wA[4][2], wB[4][2];

#define KV_LOAD_W(WBUF, KS)                                                \
  _Pragma("unroll") for (int mi_ = 0; mi_ < 4; ++mi_)                      \
    _Pragma("unroll") for (int u_ = 0; u_ < 2; ++u_)                       \
      WBUF[mi_][u_] =                                                      \
          *(const bf16x8*)(wbase + mi_ * 8192 + (KS) * 64 + u_ * 32);

#define KV_STEP(KS, CUR, NXT, WC, WN, FULL)                                \
  {                                                                        \
    if (FULL) {                                                            \
      STAGE_X(NXT, (KS) + 1);                                              \
      asm volatile("" ::: "memory");                                       \
      KV_LOAD_W(WN, (KS) + 1);                                             \
    }                                                                      \
    _Pragma("unroll") for (int u = 0; u < 2; ++u)                          \
      _Pragma("unroll") for (int ni = 0; ni < 4; ++ni) {                   \
        bf16x8 bx = frag_cvt(CUR, n_off + ni * 16 + l15, u * 8 + quad * 2);\
        _Pragma("unroll") for (int mi = 0; mi < 4; ++mi)                   \
          acc[mi][ni] = MFMA_BF16(WC[mi][u], bx, acc[mi][ni], 0, 0, 0);    \
      }                                                                    \
    if (FULL) BAR_VM8_LGKM();                                              \
  }

  STAGE_X(Xf[0], 0);
  asm volatile("" ::: "memory");
  KV_LOAD_W(wA, 0);
  BAR_VM8_LGKM();

  KV_STEP(0, Xf[0], Xf[1], wA, wB, true);
  KV_STEP(1, Xf[1], Xf[0], wB, wA, true);
  KV_STEP(2, Xf[0], Xf[1], wA, wB, true);
  KV_STEP(3, Xf[1], Xf[0], wB, wA, true);
  KV_STEP(4, Xf[0], Xf[1], wA, wB, true);
  KV_STEP(5, Xf[1], Xf[0], wB, wA, true);
  KV_STEP(6, Xf[0], Xf[1], wA, wB, true);
  KV_STEP(7, Xf[1], Xf[0], wB, wA, false);

  const int b = ng >> 12;
  const int nl0 = (ng & 4095) + n_off;
#pragma unroll
  for (int mi = 0; mi < 4; ++mi)
#pragma unroll
    for (int r = 0; r < 4; ++r) {
      const int d = d0 + d_off + mi * 16 + quad * 4 + r;
      const float bv_ = bias[d];
      bf16_t* rowp = Out + (size_t)b * 2097152 + (size_t)d * 4096 + nl0;
#pragma unroll
      for (int ni = 0; ni < 4; ++ni) {
        float v = acc[mi][ni][r] + bv_;
        if (expm) v = __expf(v * INV_D4);
        rowp[ni * 16 + l15] = (bf16_t)v;
      }
    }
#undef KV_STEP
#undef KV_LOAD_W
}

// ---------------- Sk[b*512+d] = sum_n Ft[b][d][n] (row sums) ----------------
__global__ __launch_bounds__(256) void sk_kernel(const bf16_t* __restrict__ Ft,
                                                 float* __restrict__ Sk) {
  const int row = blockIdx.x * 4 + (threadIdx.x >> 6);
  const int lane = threadIdx.x & 63;
  const bf16x8* p = (const bf16x8*)(Ft + (size_t)row * 4096) + lane;
  float s = 0.f;
#pragma unroll
  for (int j = 0; j < 8; ++j) {
    bf16x8 v = p[j * 64];
#pragma unroll
    for (int e = 0; e < 8; ++e) s += (float)v[e];
  }
#pragma unroll
  for (int m = 1; m <= 32; m <<= 1) s += __shfl_xor(s, m);
  if (lane == 0) Sk[row] = s;
}

// ---------------- Bm GEMM: Bmp[s][b][d][e] = sum_{n in slice} Ft[d][n]Vt[e][n]
__global__ __launch_bounds__(256, 2) void bm_gemm(
    const bf16_t* __restrict__ Ft, const bf16_t* __restrict__ Vt,
    float* __restrict__ Bmp, int S) {
  const int b = blockIdx.z / S;
  const int s = blockIdx.z - b * S;
  const int d0 = blockIdx.x * 128;
  const int e0 = blockIdx.y * 128;
  const bf16_t* A = Ft + (size_t)b * 2097152;
  const bf16_t* B = Vt + (size_t)b * 2097152;
  float* out = Bmp + ((size_t)s * 8 + b) * 262144;

  __shared__ __align__(16) bf16_t As[2][8192];  // row-major [128][64], swizzled
  __shared__ __align__(16) bf16_t Bs[2][8192];

  const int t = threadIdx.x;
  const int lane = t & 63, w = t >> 6;
  const int quad = lane >> 4, l15 = lane & 15;
  const int m_off = (w & 1) * 64, n_off = (w >> 1) * 64;

  const int kper = 4096 / S;
  const int KS = kper >> 6;  // K_STEP = 64
  const int kbase = s * kper;

  f32x4 acc[4][4];
  const f32x4 zero4 = {0.f, 0.f, 0.f, 0.f};
#pragma unroll
  for (int i = 0; i < 4; ++i)
#pragma unroll
    for (int j = 0; j < 4; ++j) acc[i][j] = zero4;

  const int srow = lane >> 3;                 // 0..7
  const int spiece = (lane & 7) ^ srow;       // pre-swizzled global piece
  const bf16_t* asrc = A + (size_t)(d0 + srow) * 4096 + kbase + spiece * 8;
  const bf16_t* bsrc = B + (size_t)(e0 + srow) * 4096 + kbase + spiece * 8;
  const int q0 = w * 4;
  const int rsw = l15 & 7;

  auto stage = [&](int buf, int ks) {
#pragma unroll
    for (int i = 0; i < 4; ++i) {
      const int q = q0 + i;
      async_ld16(asrc + (size_t)q * 8 * 4096 + ks * 64, &As[buf][q * 512]);
      async_ld16(bsrc + (size_t)q * 8 * 4096 + ks * 64, &Bs[buf][q * 512]);
    }
  };

  stage(0, 0);
  BAR_VM_LGKM();

  for (int ks = 0; ks < KS; ++ks) {
    const int p = ks & 1;
    if (ks + 1 < KS) stage(p ^ 1, ks + 1);
#pragma unroll
    for (int ksub = 0; ksub < 2; ++ksub) {
      const int c = ksub * 4 + quad;
      bf16x8 af[4], bfr[4];
#pragma unroll
      for (int mi = 0; mi < 4; ++mi) {
        const int row = m_off + mi * 16 + l15;
        af[mi] = *(const bf16x8*)(&As[p][(size_t)row * 64 + ((c ^ rsw) << 3)]);
      }
#pragma unroll
      for (int ni = 0; ni < 4; ++ni) {
        const int row = n_off + ni * 16 + l15;
        bfr[ni] = *(const bf16x8*)(&Bs[p][(size_t)row * 64 + ((c ^ rsw) << 3)]);
      }
#pragma unroll
      for (int mi = 0; mi < 4; ++mi)
#pragma unroll
        for (int ni = 0; ni < 4; ++ni)
          acc[mi][ni] = MFMA_BF16(af[mi], bfr[ni], acc[mi][ni], 0, 0, 0);
    }
    if (ks + 1 < KS) BAR_VM_LGKM();
  }

#pragma unroll
  for (int mi = 0; mi < 4; ++mi)
#pragma unroll
    for (int ni = 0; ni < 4; ++ni) {
      const int ecol = e0 + n_off + ni * 16 + l15;
#pragma unroll
      for (int r = 0; r < 4; ++r) {
        const int drow = d0 + m_off + mi * 16 + quad * 4 + r;
        out[(size_t)drow * 512 + ecol] = acc[mi][ni][r];
      }
    }
}

// ---------------- scale + reduce partials + transpose -----------------------
__global__ __launch_bounds__(256) void scale_kernel(
    const float* __restrict__ Bmp, const float* __restrict__ Sq,
    const float* __restrict__ Sk, bf16_t* __restrict__ Ct, int S) {
  const int b = blockIdx.z;
  const int d0 = blockIdx.x * 64, e0 = blockIdx.y * 64;
  __shared__ __align__(16) bf16_t tile[64 * 72];
  const int t = threadIdx.x;
  const int r = t >> 2;
  const int c4 = (t & 3) * 16;
  const int d = d0 + r;
  const float f = 1.0f / (Sq[b * 512 + d] * Sk[b * 512 + d]);
  const float* p0 = Bmp + (size_t)b * 262144 + (size_t)d * 512 + e0 + c4;
#pragma unroll
  for (int i = 0; i < 4; ++i) {
    float sx = 0.f, sy = 0.f, sz = 0.f, sw = 0.f;
    for (int sp = 0; sp < S; ++sp) {
      float4 v = ((const float4*)(p0 + (size_t)sp * 2097152))[i];
      sx += v.x; sy += v.y; sz += v.z; sw += v.w;
    }
    tile[(c4 + i * 4 + 0) * 72 + r] = (__bf16)(sx * f);
    tile[(c4 + i * 4 + 1) * 72 + r] = (__bf16)(sy * f);
    tile[(c4 + i * 4 + 2) * 72 + r] = (__bf16)(sz * f);
    tile[(c4 + i * 4 + 3) * 72 + r] = (__bf16)(sw * f);
  }
  __syncthreads();
  bf16x8* dst = (bf16x8*)(Ct + (size_t)b * 262144 + (size_t)(e0 + r) * 512 + d0 + c4);
  const bf16x8* sptr = (const bf16x8*)(tile + r * 72 + c4);
  dst[0] = sptr[0];
  dst[1] = sptr[1];
}

// ---------------- Z GEMM: Z[row,e]=sum_d Eq[row,d]*Ct[b][e][d], 128x256 -----
__global__ __launch_bounds__(256, 2) void z_gemm(
    const bf16_t* __restrict__ Eq, const bf16_t* __restrict__ Ct,
    float* __restrict__ out) {
  __shared__ __align__(16) bf16_t As[2][8192];  // row-major [128][64], swizzled

  const int t = threadIdx.x;
  const int lane = t & 63, w = t >> 6;
  const int quad = lane >> 4, l15 = lane & 15;
  const int m0 = blockIdx.x * 128;
  const int n0 = blockIdx.y * 256 + w * 64;
  const int batch = m0 >> 12;
  const bf16_t* Bt = Ct + (size_t)batch * 262144;

  f32x4 acc[8][4];
  const f32x4 zero4 = {0.f, 0.f, 0.f, 0.f};
#pragma unroll
  for (int i = 0; i < 8; ++i)
#pragma unroll
    for (int j = 0; j < 4; ++j) acc[i][j] = zero4;

  const int srow = lane >> 3;
  const int spiece = (lane & 7) ^ srow;
  const bf16_t* asrc = Eq + (size_t)(m0 + srow) * 512 + spiece * 8;
  const int q0 = w * 4;
  const int rsw = l15 & 7;
  const bf16_t* wbase = Bt + (size_t)(n0 + l15) * 512 + quad * 8;

  auto stageZ = [&](int buf, int ks) {
#pragma unroll
    for (int i = 0; i < 4; ++i) {
      const int q = q0 + i;
      async_ld16(asrc + (size_t)q * 8 * 512 + ks * 64, &As[buf][q * 512]);
    }
  };

  stageZ(0, 0);
  BAR_VM_LGKM();

#pragma unroll
  for (int ks = 0; ks < 8; ++ks) {
    const int p = ks & 1;
    if (ks < 7) stageZ(p ^ 1, ks + 1);
    bf16x8 wrA[4], wrB[4];
#pragma unroll
    for (int ni = 0; ni < 4; ++ni) {
      wrA[ni] = *(const bf16x8*)(wbase + ni * 8192 + ks * 64);
      wrB[ni] = *(const bf16x8*)(wbase + ni * 8192 + ks * 64 + 32);
    }
#pragma unroll
    for (int ksub = 0; ksub < 2; ++ksub) {
      const int c = ksub * 4 + quad;
      bf16x8 af[8];
#pragma unroll
      for (int mi = 0; mi < 8; ++mi) {
        const int row = mi * 16 + l15;
        af[mi] = *(const bf16x8*)(&As[p][(size_t)row * 64 + ((c ^ rsw) << 3)]);
      }
#pragma unroll
      for (int mi = 0; mi < 8; ++mi)
#pragma unroll
        for (int ni = 0; ni < 4; ++ni)
          acc[mi][ni] =
              MFMA_BF16(af[mi], ksub ? wrB[ni] : wrA[ni], acc[mi][ni], 0, 0, 0);
    }
    if (ks < 7) BAR_VM_LGKM();
  }

#pragma unroll
  for (int mi = 0; mi < 8; ++mi)
#pragma unroll
    for (int ni = 0; ni < 4; ++ni) {
      const int col = n0 + ni * 16 + l15;
#pragma unroll
      for (int r = 0; r < 4; ++r) {
        const int row = m0 + mi * 16 + quad * 4 + r;
        out[(size_t)row * 512 + col] = acc[mi][ni][r];
      }
    }
}

extern "C" void kernel_launch(void* const* d_in, const int* in_sizes, int n_in,
                              void* d_out, int out_size, void* d_ws,
                              size_t ws_size, hipStream_t stream) {
  const float* xq = (const float*)d_in[0];
  const float* xk = (const float*)d_in[1];
  const float* xv = (const float*)d_in[2];
  const float* Wq = (const float*)d_in[3];
  const float* bq = (const float*)d_in[4];
  const float* Wk = (const float*)d_in[5];
  const float* bk = (const float*)d_in[6];
  const float* Wv = (const float*)d_in[7];
  const float* bv = (const float*)d_in[8];
  float* out = (float*)d_out;

  char* ws = (char*)d_ws;
  bf16_t* Eq = (bf16_t*)(ws + 0);           // 8x4096x512 bf16  33,554,432 B
  bf16_t* Ft = (bf16_t*)(ws + 33554432);    // 8x512x4096 bf16 (F transposed)
  bf16_t* Vt = (bf16_t*)(ws + 67108864);    // 8x512x4096 bf16 (V transposed)
  float* Bmp = (float*)(ws + 100663296);    // S x 8x512x512 f32 split-K partials

  const int S = (ws_size >= (size_t)135823360) ? 4 : 2;
  const size_t wt_off = (S == 4) ? (size_t)134217728 : (size_t)117440512;
  bf16_t* Wt = (bf16_t*)(ws + wt_off);                  // 3x512x512 bf16
  float* Sq = (float*)(ws + wt_off + 1572864);          // 8x512 f32
  float* Sk = (float*)(ws + wt_off + 1572864 + 16384);  // 8x512 f32
  bf16_t* Ct = (bf16_t*)(ws + 33554432);    // aliases Ft (dead after bm_gemm)

  hipMemsetAsync(Sq, 0, 16384, stream);  // Sq atomic target only

  wt_kernel<<<dim3(8, 8, 3), 256, 0, stream>>>(Wq, Wk, Wv, Wt);
  proj_q<<<dim3(256, 4), 256, 0, stream>>>(xq, Wt, bq, Eq, Sq);
  proj_kv<<<dim3(256, 4, 2), 256, 0, stream>>>(xk, xv, Wt, bk, bv, Ft, Vt);
  sk_kernel<<<dim3(1024), 256, 0, stream>>>(Ft, Sk);
  bm_gemm<<<dim3(4, 4, 8 * S), 256, 0, stream>>>(Ft, Vt, Bmp, S);
  scale_kernel<<<dim3(8, 8, 8), 256, 0, stream>>>(Bmp, Sq, Sk, Ct, S);
  z_gemm<<<dim3(256, 2), 256, 0, stream>>>(Eq, Ct, out);
}